// Round 1
// baseline (528.388 us; speedup 1.0000x reference)
//
#include <hip/hip_runtime.h>
#include <math.h>

#define NB 2048
#define MM_ 5
#define SS 128
#define NN 128
#define DIN_ 64
#define CC 32
#define MIDS 16

// workspace float offsets
#define PRE_WAL 0
#define PRE_WBL 1024
#define PRE_WEFF 2048
#define PRE_BWA 2112
#define PRE_BWB 2128
#define PRE_C0 2144
#define WS_BNPART 4096              // 2048*64 floats
#define WS_COEF (4096 + 131072)     // 64 floats

// ---------------------------------------------------------------- k0: fold weights
__global__ __launch_bounds__(256) void k0_pre(const float* __restrict__ W_lin,
                                              const float* __restrict__ b_lin,
                                              const float* __restrict__ W_att,
                                              const float* __restrict__ Wa,
                                              const float* __restrict__ Wb,
                                              float* __restrict__ pre) {
  int t = threadIdx.x;
  for (int i = t; i < 1024; i += 256) {
    int o = i >> 6, d = i & 63;
    float sa = 0.f, sb = 0.f;
    for (int c = 0; c < 32; ++c) {
      float wl = W_lin[c * 64 + d];
      sa += Wa[o * 32 + c] * wl;
      sb += Wb[o * 32 + c] * wl;
    }
    pre[PRE_WAL + i] = sa;
    pre[PRE_WBL + i] = sb;
  }
  if (t < 64) {
    float s = 0.f;
    for (int c = 0; c < 32; ++c) s += W_att[c] * W_lin[c * 64 + t];
    pre[PRE_WEFF + t] = s;
  }
  if (t < 16) {
    float sa = 0.f, sb = 0.f;
    for (int c = 0; c < 32; ++c) {
      sa += Wa[t * 32 + c] * b_lin[c];
      sb += Wb[t * 32 + c] * b_lin[c];
    }
    pre[PRE_BWA + t] = sa;
    pre[PRE_BWB + t] = sb;
  }
  if (t == 0) {
    float s = 0.f;
    for (int c = 0; c < 32; ++c) s += W_att[c] * b_lin[c];
    pre[PRE_C0] = s;
  }
}

// ---------------------------------------------------------------- k1: per-batch fused module
__global__ __launch_bounds__(256, 2) void k1_main(
    const float* __restrict__ xg_all, const float* __restrict__ xl_all,
    const float* __restrict__ Wc_g, const float* __restrict__ Wn_g,
    const float* __restrict__ Wl_g, const float* __restrict__ Wd_g,
    const float* __restrict__ pre, float* __restrict__ feat_t,
    float* __restrict__ bn_part) {
  __shared__ float s_WaL[16][64];
  __shared__ float s_WbL[16][64];
  __shared__ float s_weff[64];
  __shared__ float s_Wc[16][33];
  __shared__ float s_Wd[32][33];
  __shared__ float s_bWa[16];
  __shared__ float s_bWb[16];
  __shared__ float s_c0;
  __shared__ float att_row[128];
  __shared__ float sms_row[128];
  __shared__ float sMx[128];
  __shared__ float sZ[128];
  __shared__ float s_scale[128];
  __shared__ float s_wv[128];
  __shared__ float xagg_inter[5][64];
  __shared__ float scratch[8][64];
  __shared__ float s_inter2[16][5];
  __shared__ float s_intra2[16][128];
  __shared__ float s_vinter[5][16];
  __shared__ float red2[4];
  __shared__ float ra[8576];  // phase-shared region (34304 B)

  float (*xchunk)[65]  = (float(*)[65])ra;           // phase 1: x_local m-chunk
  float (*xaggi)[65]   = (float(*)[65])ra;           // phase 2: xagg_intra
  float (*v_intra)[17] = (float(*)[17])ra;           // phase 3
  float (*xlog)[17]    = (float(*)[17])(ra + 2176);  // phase 3
  float (*ff)[33]      = (float(*)[33])(ra + 4352);  // phase 3: concat features

  const int t = threadIdx.x;
  const int b = blockIdx.x;
  const float* xl = xl_all + (size_t)b * (MM_ * SS * DIN_);
  const float* xg = xg_all + (size_t)b * (NN * CC);

  for (int i = t; i < 1024; i += 256) {
    ((float*)s_WaL)[i] = pre[PRE_WAL + i];
    ((float*)s_WbL)[i] = pre[PRE_WBL + i];
    s_Wd[i >> 5][i & 31] = Wd_g[i];
  }
  for (int i = t; i < 512; i += 256) s_Wc[i >> 5][i & 31] = Wc_g[i];
  if (t < 64) s_weff[t] = pre[PRE_WEFF + t];
  if (t < 16) { s_bWa[t] = pre[PRE_BWA + t]; s_bWb[t] = pre[PRE_BWB + t]; }
  if (t == 0) s_c0 = pre[PRE_C0];
  if (t < 128) { sMx[t] = -INFINITY; sZ[t] = 0.f; }
  __syncthreads();

  const int d_ = t & 63;
  const int sq = t >> 6;
  float acc[32];  // online intra accumulator: (s = sq + 4k, d_)
  #pragma unroll
  for (int k = 0; k < 32; ++k) acc[k] = 0.f;

  for (int m = 0; m < MM_; ++m) {
    // stage x_local chunk (128 x 64) into padded LDS
    const float4* src = (const float4*)(xl + (size_t)m * SS * DIN_);
    for (int i = t; i < 2048; i += 256) {
      float4 v = src[i];
      float* dst = &xchunk[i >> 4][(i & 15) << 2];
      dst[0] = v.x; dst[1] = v.y; dst[2] = v.z; dst[3] = v.w;
    }
    __syncthreads();
    // att[m][s] = x . w_eff + c0
    {
      int s = t >> 1, h = t & 1;
      float p = 0.f;
      #pragma unroll
      for (int j = 0; j < 32; ++j) p += xchunk[s][h * 32 + j] * s_weff[h * 32 + j];
      p += __shfl_xor(p, 1);
      if (h == 0) att_row[s] = p + s_c0;
    }
    __syncthreads();
    // softmax over s (this m): max
    float e_val = 0.f;
    if (t < 128) {
      float mx = att_row[t];
      #pragma unroll
      for (int i = 1; i < 64; i <<= 1) mx = fmaxf(mx, __shfl_xor(mx, i));
      if ((t & 63) == 0) red2[t >> 6] = mx;
    }
    __syncthreads();
    if (t < 128) {
      float rmax = fmaxf(red2[0], red2[1]);
      e_val = __expf(att_row[t] - rmax);
      float ss = e_val;
      #pragma unroll
      for (int i = 1; i < 64; i <<= 1) ss += __shfl_xor(ss, i);
      if ((t & 63) == 0) red2[2 + (t >> 6)] = ss;
    }
    __syncthreads();
    if (t < 128) {
      sms_row[t] = e_val / (red2[2] + red2[3]);
      // online softmax over m (per s)
      float a = att_row[t];
      float oldM = sMx[t];
      float nm = fmaxf(oldM, a);
      float scl = __expf(oldM - nm);   // m==0: exp(-inf)=0
      float w = __expf(a - nm);
      sZ[t] = sZ[t] * scl + w;
      sMx[t] = nm;
      s_scale[t] = scl;
      s_wv[t] = w;
    }
    __syncthreads();
    // aggregations
    {
      float p = 0.f;
      #pragma unroll 8
      for (int k = 0; k < 32; ++k) {
        int s = sq * 32 + k;
        p += sms_row[s] * xchunk[s][d_];
      }
      scratch[sq][d_] = p;
      #pragma unroll
      for (int k = 0; k < 32; ++k) {
        int s = sq + (k << 2);
        acc[k] = acc[k] * s_scale[s] + s_wv[s] * xchunk[s][d_];
      }
    }
    __syncthreads();
    if (t < 64) xagg_inter[m][t] = scratch[0][t] + scratch[1][t] + scratch[2][t] + scratch[3][t];
    __syncthreads();
  }

  // xagg_intra = acc / Z  (overwrites xchunk region)
  #pragma unroll
  for (int k = 0; k < 32; ++k) {
    int s = sq + (k << 2);
    xaggi[s][d_] = acc[k] / sZ[s];
  }
  __syncthreads();

  // inter2[o][m], intra2[o][s]
  if (t < 80) {
    int o = t / 5, mm = t % 5;
    float p = s_bWa[o];
    #pragma unroll 16
    for (int d = 0; d < 64; ++d) p += s_WaL[o][d] * xagg_inter[mm][d];
    s_inter2[o][mm] = p;
  }
  for (int it = 0; it < 8; ++it) {
    int idx = (it << 8) + t;
    int o = idx >> 7, s = idx & 127;
    float p = s_bWb[o];
    #pragma unroll 16
    for (int d = 0; d < 64; ++d) p += s_WbL[o][d] * xaggi[s][d];
    s_intra2[o][s] = p;
  }
  __syncthreads();

  // v_inter, v_intra, xlog  (v_intra/xlog overwrite xaggi region — dead now)
  if (t < 80) {
    int mm = t >> 4, p = t & 15;
    float v = 0.f;
    #pragma unroll
    for (int o = 0; o < 16; ++o) v += Wn_g[p * 16 + o] * s_inter2[o][mm];
    s_vinter[mm][p] = v;
  }
  for (int it = 0; it < 8; ++it) {
    int idx = (it << 8) + t;
    int s = idx >> 4, p = idx & 15;
    float v = 0.f;
    #pragma unroll
    for (int o = 0; o < 16; ++o) v += Wl_g[p * 16 + o] * s_intra2[o][s];
    v_intra[s][p] = v;
  }
  for (int it = 0; it < 8; ++it) {
    int idx = (it << 8) + t;
    int n = idx >> 4, o = idx & 15;
    float v = 0.f;
    #pragma unroll
    for (int c = 0; c < 32; ++c) v += s_Wc[o][c] * xg[n * 32 + c];
    xlog[n][o] = v;
  }
  __syncthreads();

  // f_inter (t<128: one thread per n)
  if (t < 128) {
    int n = t;
    float xr[16];
    #pragma unroll
    for (int o = 0; o < 16; ++o) xr[o] = xlog[n][o];
    float L[5];
    float mx = -1e30f;
    #pragma unroll
    for (int mm = 0; mm < 5; ++mm) {
      float p = 0.f;
      #pragma unroll
      for (int o = 0; o < 16; ++o) p += xr[o] * s_inter2[o][mm];
      L[mm] = p;
      mx = fmaxf(mx, p);
    }
    float sum = 0.f;
    #pragma unroll
    for (int mm = 0; mm < 5; ++mm) { L[mm] = __expf(L[mm] - mx); sum += L[mm]; }
    float inv = 1.f / sum;
    #pragma unroll
    for (int p = 0; p < 16; ++p) {
      float v = 0.f;
      #pragma unroll
      for (int mm = 0; mm < 5; ++mm) v += L[mm] * s_vinter[mm][p];
      ff[n][p] = v * inv;
    }
  }
  // f_intra (2 threads per n, recompute logits to avoid a 64-reg array)
  {
    int n = t >> 1, h = t & 1;
    float xr[16];
    #pragma unroll
    for (int o = 0; o < 16; ++o) xr[o] = xlog[n][o];
    float mx = -1e30f;
    for (int i = 0; i < 64; ++i) {
      int s = h * 64 + i;
      float p = 0.f;
      #pragma unroll
      for (int o = 0; o < 16; ++o) p += xr[o] * s_intra2[o][s];
      mx = fmaxf(mx, p);
    }
    mx = fmaxf(mx, __shfl_xor(mx, 1));
    float fa[16];
    #pragma unroll
    for (int p = 0; p < 16; ++p) fa[p] = 0.f;
    float sum = 0.f;
    for (int i = 0; i < 64; ++i) {
      int s = h * 64 + i;
      float p = 0.f;
      #pragma unroll
      for (int o = 0; o < 16; ++o) p += xr[o] * s_intra2[o][s];
      float e = __expf(p - mx);
      sum += e;
      #pragma unroll
      for (int pp = 0; pp < 16; ++pp) fa[pp] += e * v_intra[s][pp];
    }
    sum += __shfl_xor(sum, 1);
    float inv = 1.f / sum;
    #pragma unroll
    for (int p = 0; p < 16; ++p) {
      float v = fa[p] + __shfl_xor(fa[p], 1);
      if (h == 0) ff[n][16 + p] = v * inv;
    }
  }
  __syncthreads();

  // feat (pre-BN) in [B,N,C] layout directly into d_out, plus BN partials
  {
    int o = t & 31, nc = t >> 5;
    float s1 = 0.f, s2 = 0.f;
    for (int k = 0; k < 16; ++k) {
      int n = nc * 16 + k;
      float v = 0.f;
      #pragma unroll
      for (int c = 0; c < 32; ++c) v += s_Wd[o][c] * ff[n][c];
      feat_t[((size_t)b * NN + n) * CC + o] = v;
      s1 += v;
      s2 += v * v;
    }
    scratch[nc][o] = s1;
    scratch[nc][o + 32] = s2;
  }
  __syncthreads();
  if (t < 64) {
    float s = 0.f;
    #pragma unroll
    for (int k = 0; k < 8; ++k) s += scratch[k][t];
    bn_part[b * 64 + t] = s;
  }
}

// ---------------------------------------------------------------- k2: BN coefficients
__global__ __launch_bounds__(256) void k2_stats(const float* __restrict__ bn_part,
                                                const float* __restrict__ gamma,
                                                const float* __restrict__ beta,
                                                float* __restrict__ coef) {
  __shared__ float sc[4][64];
  int t = threadIdx.x;
  int c = t & 63, q = t >> 6;
  float s = 0.f;
  for (int b = q; b < NB; b += 4) s += bn_part[b * 64 + c];
  sc[q][c] = s;
  __syncthreads();
  if (t < 64) sc[0][t] = sc[0][t] + sc[1][t] + sc[2][t] + sc[3][t];
  __syncthreads();
  if (t < 32) {
    const float inv = 1.f / (float)(NB * NN);
    float mean = sc[0][t] * inv;
    float var = sc[0][t + 32] * inv - mean * mean;
    float scl = gamma[t] * rsqrtf(var + 1e-5f);
    coef[t] = scl;
    coef[32 + t] = beta[t] - mean * scl;
  }
}

// ---------------------------------------------------------------- k3: BN apply + residual + leaky (in place on d_out)
__global__ __launch_bounds__(256) void k3_final(const float* __restrict__ xg,
                                                float* __restrict__ out,
                                                const float* __restrict__ coef) {
  __shared__ float s_c[64];
  if (threadIdx.x < 64) s_c[threadIdx.x] = coef[threadIdx.x];
  __syncthreads();
  size_t i4 = (size_t)blockIdx.x * 256 + threadIdx.x;  // 8192*256 = 2097152 float4s exactly
  float4 f = ((const float4*)out)[i4];
  float4 x = ((const float4*)xg)[i4];
  int c = (int)((i4 * 4) & 31);
  float4 r;
  r.x = x.x + f.x * s_c[c + 0] + s_c[32 + c + 0];
  r.y = x.y + f.y * s_c[c + 1] + s_c[32 + c + 1];
  r.z = x.z + f.z * s_c[c + 2] + s_c[32 + c + 2];
  r.w = x.w + f.w * s_c[c + 3] + s_c[32 + c + 3];
  r.x = r.x >= 0.f ? r.x : 0.2f * r.x;
  r.y = r.y >= 0.f ? r.y : 0.2f * r.y;
  r.z = r.z >= 0.f ? r.z : 0.2f * r.z;
  r.w = r.w >= 0.f ? r.w : 0.2f * r.w;
  ((float4*)out)[i4] = r;
}

// ----------------------------------------------------------------
extern "C" void kernel_launch(void* const* d_in, const int* in_sizes, int n_in,
                              void* d_out, int out_size, void* d_ws, size_t ws_size,
                              hipStream_t stream) {
  const float* xg    = (const float*)d_in[0];
  const float* xl    = (const float*)d_in[1];
  const float* W_lin = (const float*)d_in[2];
  const float* b_lin = (const float*)d_in[3];
  const float* W_att = (const float*)d_in[4];
  const float* Wa    = (const float*)d_in[5];
  const float* Wb    = (const float*)d_in[6];
  const float* Wc    = (const float*)d_in[7];
  const float* Wn    = (const float*)d_in[8];
  const float* Wl    = (const float*)d_in[9];
  const float* Wd    = (const float*)d_in[10];
  const float* gamma = (const float*)d_in[11];
  const float* beta  = (const float*)d_in[12];
  float* out = (float*)d_out;
  float* ws = (float*)d_ws;
  float* pre = ws;
  float* bn_part = ws + WS_BNPART;
  float* coef = ws + WS_COEF;

  hipLaunchKernelGGL(k0_pre, dim3(1), dim3(256), 0, stream, W_lin, b_lin, W_att, Wa, Wb, pre);
  hipLaunchKernelGGL(k1_main, dim3(NB), dim3(256), 0, stream, xg, xl, Wc, Wn, Wl, Wd, pre, out, bn_part);
  hipLaunchKernelGGL(k2_stats, dim3(1), dim3(256), 0, stream, bn_part, gamma, beta, coef);
  hipLaunchKernelGGL(k3_final, dim3(8192), dim3(256), 0, stream, xg, out, coef);
}

// Round 2
// 361.918 us; speedup vs baseline: 1.4600x; 1.4600x over previous
//
#include <hip/hip_runtime.h>
#include <math.h>

#define NB 2048

// pre[] float offsets (folded weights)
#define P_WAL 0
#define P_WBL 1024
#define P_WLBL 2048
#define P_WNAL 3072
#define P_WEFF 4096
#define P_BWA 4160
#define P_BWB 4176
#define P_BWL 4192
#define P_BWN 4208
#define P_C0  4224

// ws float offsets
#define WS_BNPART 4352
#define WS_COEF   135424
#define WS_SMALL  135488
#define WS_BIG_I  463168      // uint region [2048][1024] (bf16 pairs: intra2T)
#define WS_BIG_V  2560320     // uint region [2048][1024] (bf16 pairs: v_intra)

__device__ __forceinline__ unsigned short f2bf(float f) {
  unsigned int u = __float_as_uint(f);
  u += 0x7fffu + ((u >> 16) & 1u);
  return (unsigned short)(u >> 16);
}
__device__ __forceinline__ unsigned int pack2bf(float lo, float hi) {
  return (unsigned int)f2bf(lo) | ((unsigned int)f2bf(hi) << 16);
}
__device__ __forceinline__ float bflo(unsigned int u) { return __uint_as_float(u << 16); }
__device__ __forceinline__ float bfhi(unsigned int u) { return __uint_as_float(u & 0xffff0000u); }

// segmented butterfly: reduces a[HALF*2] over lanes, halving regs per stage
#define BSTAGE(MASK, HALF)                                        \
  { const bool hi_ = (lane & (MASK)) != 0;                        \
    _Pragma("unroll")                                             \
    for (int k_ = 0; k_ < (HALF); ++k_) {                         \
      float mine_ = hi_ ? a[k_ + (HALF)] : a[k_];                 \
      float oth_  = hi_ ? a[k_] : a[k_ + (HALF)];                 \
      a[k_] = mine_ + __shfl_xor(oth_, (MASK));                   \
    } }

// ---------------------------------------------------------------- k0: fold weights
__global__ __launch_bounds__(256) void k0_pre(const float* __restrict__ W_lin,
                                              const float* __restrict__ b_lin,
                                              const float* __restrict__ W_att,
                                              const float* __restrict__ Wa,
                                              const float* __restrict__ Wb,
                                              const float* __restrict__ Wn,
                                              const float* __restrict__ Wl,
                                              float* __restrict__ pre) {
  int t = threadIdx.x;
  for (int i = t; i < 1024; i += 256) {
    int o = i >> 6, d = i & 63;
    float sa = 0.f, sb = 0.f;
    for (int c = 0; c < 32; ++c) {
      float wl = W_lin[c * 64 + d];
      sa += Wa[o * 32 + c] * wl;
      sb += Wb[o * 32 + c] * wl;
    }
    pre[P_WAL + i] = sa;
    pre[P_WBL + i] = sb;
  }
  if (t < 64) {
    float s = 0.f;
    for (int c = 0; c < 32; ++c) s += W_att[c] * W_lin[c * 64 + t];
    pre[P_WEFF + t] = s;
  }
  if (t < 16) {
    float sa = 0.f, sb = 0.f;
    for (int c = 0; c < 32; ++c) {
      sa += Wa[t * 32 + c] * b_lin[c];
      sb += Wb[t * 32 + c] * b_lin[c];
    }
    pre[P_BWA + t] = sa;
    pre[P_BWB + t] = sb;
  }
  if (t == 0) {
    float s = 0.f;
    for (int c = 0; c < 32; ++c) s += W_att[c] * b_lin[c];
    pre[P_C0] = s;
  }
  __syncthreads();
  // second stage: fold Wl*WbL, Wn*WaL
  for (int i = t; i < 1024; i += 256) {
    int p_ = i >> 6, d = i & 63;
    float sl = 0.f, sn = 0.f;
    for (int o = 0; o < 16; ++o) {
      sl += Wl[p_ * 16 + o] * pre[P_WBL + o * 64 + d];
      sn += Wn[p_ * 16 + o] * pre[P_WAL + o * 64 + d];
    }
    pre[P_WLBL + i] = sl;
    pre[P_WNAL + i] = sn;
  }
  if (t < 16) {
    float sl = 0.f, sn = 0.f;
    for (int o = 0; o < 16; ++o) {
      sl += Wl[t * 16 + o] * pre[P_BWB + o];
      sn += Wn[t * 16 + o] * pre[P_BWA + o];
    }
    pre[P_BWL + t] = sl;
    pre[P_BWN + t] = sn;
  }
}

// ---------------------------------------------------------------- k1a: per-batch softmax aggregation + projections
__global__ __launch_bounds__(256, 4) void k1a(
    const float* __restrict__ xl_all, const float* __restrict__ pre,
    float* __restrict__ p_small, unsigned int* __restrict__ bigI,
    unsigned int* __restrict__ bigV) {
  __shared__ float att_row[128];
  __shared__ float4 s_smw[128];
  __shared__ float sMx[128];
  __shared__ float sZ[128];
  __shared__ float red2[4];
  __shared__ float scratch[4][64];
  __shared__ float xagg_inter[5][64];
  __shared__ __align__(16) char u_region[16896];
  unsigned short* xaggi = (unsigned short*)u_region;   // [128][66] bf16
  float (*pcomb)[32] = (float (*)[32])u_region;        // reuse: [128][32] f32

  const int t = threadIdx.x;
  const int b = blockIdx.x;
  const int lane = t & 63;
  const int w = t >> 6;
  const float* xl = xl_all + (size_t)b * (5 * 128 * 64);

  const float weff_r = pre[P_WEFF + lane];
  const float c0 = pre[P_C0];
  const int kmap = ((lane & 1) << 4) | ((lane & 2) << 2) | (lane & 4) |
                   ((lane >> 2) & 2) | ((lane >> 4) & 1);

  if (t < 128) { sMx[t] = -INFINITY; sZ[t] = 0.f; }
  __syncthreads();

  float acc[32];
  #pragma unroll
  for (int k = 0; k < 32; ++k) acc[k] = 0.f;
  float x_reg[32];

  for (int m = 0; m < 5; ++m) {
    const float* xp = xl + (size_t)(m * 128 + 32 * w) * 64 + lane;
    #pragma unroll
    for (int k = 0; k < 32; ++k) x_reg[k] = xp[k * 64];
    // att via segmented butterfly: 32 row-dots over 64 lanes
    {
      float a[32];
      #pragma unroll
      for (int k = 0; k < 32; ++k) a[k] = x_reg[k] * weff_r;
      BSTAGE(1, 16) BSTAGE(2, 8) BSTAGE(4, 4) BSTAGE(8, 2) BSTAGE(16, 1)
      a[0] += __shfl_xor(a[0], 32);
      if (lane < 32) att_row[w * 32 + kmap] = a[0] + c0;
    }
    __syncthreads();
    float e_val = 0.f, a_att = 0.f;
    if (t < 128) {
      a_att = att_row[t];
      float mx = a_att;
      #pragma unroll
      for (int i = 1; i < 64; i <<= 1) mx = fmaxf(mx, __shfl_xor(mx, i));
      if ((t & 63) == 0) red2[t >> 6] = mx;
    } else if (t < 192 && m > 0) {
      int d = t - 128;
      xagg_inter[m - 1][d] = scratch[0][d] + scratch[1][d] + scratch[2][d] + scratch[3][d];
    }
    __syncthreads();
    if (t < 128) {
      float rmax = fmaxf(red2[0], red2[1]);
      e_val = __expf(a_att - rmax);
      float ssum = e_val;
      #pragma unroll
      for (int i = 1; i < 64; i <<= 1) ssum += __shfl_xor(ssum, i);
      if ((t & 63) == 0) red2[2 + (t >> 6)] = ssum;
    }
    __syncthreads();
    if (t < 128) {
      float sms = e_val / (red2[2] + red2[3]);
      float oldM = sMx[t];
      float nm = fmaxf(oldM, a_att);
      float scl = __expf(oldM - nm);
      float wv = __expf(a_att - nm);
      sZ[t] = sZ[t] * scl + wv;
      sMx[t] = nm;
      s_smw[t] = make_float4(sms, scl, wv, 0.f);
    }
    __syncthreads();
    // aggregation (inter partial + online intra accumulate)
    {
      float pi = 0.f;
      #pragma unroll
      for (int k = 0; k < 32; ++k) {
        float4 q = s_smw[32 * w + k];
        pi += q.x * x_reg[k];
        acc[k] = acc[k] * q.y + q.z * x_reg[k];
      }
      scratch[w][lane] = pi;
    }
    __syncthreads();
  }

  // combine last m's inter partial; normalize intra acc -> xaggi (bf16 LDS)
  if (t < 64)
    xagg_inter[4][t] = scratch[0][t] + scratch[1][t] + scratch[2][t] + scratch[3][t];
  #pragma unroll
  for (int k = 0; k < 32; ++k) {
    float z = sZ[32 * w + k];
    xaggi[(32 * w + k) * 66 + lane] = f2bf(acc[k] / z);
  }
  __syncthreads();
  // transpose read: thread -> (s2, d-half)
  const int s2 = 64 * (w >> 1) + lane;
  const int hf = w & 1;
  float xa[32];
  #pragma unroll
  for (int j = 0; j < 16; ++j) {
    unsigned int pr = *(const unsigned int*)&xaggi[s2 * 66 + 32 * hf + 2 * j];
    xa[2 * j] = bflo(pr);
    xa[2 * j + 1] = bfhi(pr);
  }
  __syncthreads();
  // 32 projections (intra2 rows 0..15, v_intra rows 16..31), weights via scalar loads
  const int hfu = __builtin_amdgcn_readfirstlane(hf);
  float acc2[32];
  #pragma unroll
  for (int r = 0; r < 16; ++r) {
    const float* wr = pre + P_WBL + r * 64 + 32 * hfu;
    float p = 0.f;
    #pragma unroll
    for (int j = 0; j < 32; ++j) p += xa[j] * wr[j];
    acc2[r] = p;
  }
  #pragma unroll
  for (int r = 0; r < 16; ++r) {
    const float* wr = pre + P_WLBL + r * 64 + 32 * hfu;
    float p = 0.f;
    #pragma unroll
    for (int j = 0; j < 32; ++j) p += xa[j] * wr[j];
    acc2[16 + r] = p;
  }
  if (hf == 0) {
    #pragma unroll
    for (int r = 0; r < 32; ++r) pcomb[s2][r] = acc2[r];
  }
  __syncthreads();
  if (hf == 1) {
    unsigned int* oI = bigI + (size_t)b * 1024 + s2 * 8;
    unsigned int* oV = bigV + (size_t)b * 1024 + s2 * 8;
    #pragma unroll
    for (int j = 0; j < 8; ++j) {
      float v0 = acc2[2 * j] + pcomb[s2][2 * j] + pre[P_BWB + 2 * j];
      float v1 = acc2[2 * j + 1] + pcomb[s2][2 * j + 1] + pre[P_BWB + 2 * j + 1];
      oI[j] = pack2bf(v0, v1);
    }
    #pragma unroll
    for (int j = 0; j < 8; ++j) {
      float v0 = acc2[16 + 2 * j] + pcomb[s2][16 + 2 * j] + pre[P_BWL + 2 * j];
      float v1 = acc2[16 + 2 * j + 1] + pcomb[s2][16 + 2 * j + 1] + pre[P_BWL + 2 * j + 1];
      oV[j] = pack2bf(v0, v1);
    }
  }
  // inter projections (tiny): inter2T[5][16] then v_inter[5][16]
  if (t < 160) {
    int o2 = t & 31, mm = t >> 5;
    const float* wr = pre + ((o2 < 16) ? (P_WAL + o2 * 64) : (P_WNAL + (o2 - 16) * 64));
    float p = 0.f;
    #pragma unroll
    for (int d = 0; d < 64; ++d) p += wr[d] * xagg_inter[mm][d];
    p += (o2 < 16) ? pre[P_BWA + o2] : pre[P_BWN + (o2 - 16)];
    float* os = p_small + (size_t)b * 160;
    if (o2 < 16) os[mm * 16 + o2] = p;
    else os[80 + mm * 16 + (o2 - 16)] = p;
  }
}

// ---------------------------------------------------------------- k1b: attention + feat + BN partials
__global__ __launch_bounds__(256, 4) void k1b(
    const float* __restrict__ xg_all, const float* __restrict__ Wc_g,
    const float* __restrict__ Wd_g, const float* __restrict__ p_small,
    const unsigned int* __restrict__ bigI, const unsigned int* __restrict__ bigV,
    float* __restrict__ out, float* __restrict__ bn_part) {
  __shared__ float comb[256][19];
  __shared__ float part[4][32];

  const int t = threadIdx.x;
  const int b = blockIdx.x;
  const int n = t & 127;
  const int sh = t >> 7;       // which s-half this thread sums
  const int w = t >> 6;
  const int lane = t & 63;
  const int kmap = ((lane & 1) << 4) | ((lane & 2) << 2) | (lane & 4) |
                   ((lane >> 2) & 2) | ((lane >> 4) & 1);
  const float* xg = xg_all + (size_t)b * (128 * 32);

  // xlog[n][0..15]
  float xc[32];
  const float4* xr = (const float4*)(xg + n * 32);
  #pragma unroll
  for (int q = 0; q < 8; ++q) {
    float4 v = xr[q];
    xc[4 * q] = v.x; xc[4 * q + 1] = v.y; xc[4 * q + 2] = v.z; xc[4 * q + 3] = v.w;
  }
  float xlog[16];
  #pragma unroll
  for (int o = 0; o < 16; ++o) {
    float p = 0.f;
    #pragma unroll
    for (int c = 0; c < 32; ++c) p += Wc_g[o * 32 + c] * xc[c];
    xlog[o] = p;
  }

  // online softmax over this thread's s-half (wave-uniform rows -> scalar loads)
  const int shu = __builtin_amdgcn_readfirstlane(sh);
  const unsigned int* Ib = bigI + (size_t)b * 1024 + shu * 512;
  const unsigned int* Vb = bigV + (size_t)b * 1024 + shu * 512;
  float mx = -INFINITY, sum = 0.f;
  float fa[16];
  #pragma unroll
  for (int j = 0; j < 16; ++j) fa[j] = 0.f;
  for (int i = 0; i < 64; ++i) {
    float p = 0.f;
    #pragma unroll
    for (int q = 0; q < 8; ++q) {
      unsigned int u = Ib[i * 8 + q];
      p += xlog[2 * q] * bflo(u) + xlog[2 * q + 1] * bfhi(u);
    }
    float nm = fmaxf(mx, p);
    float scl = __expf(mx - nm);
    float e = __expf(p - nm);
    sum = sum * scl + e;
    #pragma unroll
    for (int q = 0; q < 8; ++q) {
      unsigned int u = Vb[i * 8 + q];
      fa[2 * q] = fa[2 * q] * scl + e * bflo(u);
      fa[2 * q + 1] = fa[2 * q + 1] * scl + e * bfhi(u);
    }
    mx = nm;
  }
  // merge the two halves (cross-wave partner) via LDS
  comb[t][0] = mx;
  comb[t][1] = sum;
  #pragma unroll
  for (int j = 0; j < 16; ++j) comb[t][2 + j] = fa[j];
  __syncthreads();
  const int pt = t ^ 128;
  float mx2 = comb[pt][0], sum2 = comb[pt][1];
  float nm = fmaxf(mx, mx2);
  float c1 = __expf(mx - nm), c2 = __expf(mx2 - nm);
  float inv = 1.f / (sum * c1 + sum2 * c2);
  float fint[16];
  #pragma unroll
  for (int j = 0; j < 16; ++j) fint[j] = (fa[j] * c1 + comb[pt][2 + j] * c2) * inv;

  // f_inter (5-way softmax), computed redundantly by both partners
  const float* sm = p_small + (size_t)b * 160;
  float L[5], mx3 = -1e30f;
  #pragma unroll
  for (int mm = 0; mm < 5; ++mm) {
    float p = 0.f;
    #pragma unroll
    for (int o = 0; o < 16; ++o) p += xlog[o] * sm[mm * 16 + o];
    L[mm] = p;
    mx3 = fmaxf(mx3, p);
  }
  float sum3 = 0.f;
  #pragma unroll
  for (int mm = 0; mm < 5; ++mm) { L[mm] = __expf(L[mm] - mx3); sum3 += L[mm]; }
  float inv3 = 1.f / sum3;
  float fi[16];
  #pragma unroll
  for (int j = 0; j < 16; ++j) {
    float p = 0.f;
    #pragma unroll
    for (int mm = 0; mm < 5; ++mm) p += L[mm] * sm[80 + mm * 16 + j];
    fi[j] = p * inv3;
  }

  // feat for o in [16*sh, 16*sh+16)
  float feat[16];
  #pragma unroll
  for (int j = 0; j < 16; ++j) {
    int o = 16 * sh + j;
    float p = 0.f;
    #pragma unroll
    for (int c = 0; c < 16; ++c) p += Wd_g[o * 32 + c] * fi[c];
    #pragma unroll
    for (int c = 0; c < 16; ++c) p += Wd_g[o * 32 + 16 + c] * fint[c];
    feat[j] = p;
  }
  float* op = out + ((size_t)b * 128 + n) * 32 + 16 * sh;
  #pragma unroll
  for (int q = 0; q < 4; ++q)
    ((float4*)op)[q] = make_float4(feat[4 * q], feat[4 * q + 1], feat[4 * q + 2], feat[4 * q + 3]);

  // BN partials: butterfly-reduce 32 values (s1[16], s2[16]) over 64 lanes (= 64 n)
  {
    float a[32];
    #pragma unroll
    for (int j = 0; j < 16; ++j) { a[j] = feat[j]; a[16 + j] = feat[j] * feat[j]; }
    BSTAGE(1, 16) BSTAGE(2, 8) BSTAGE(4, 4) BSTAGE(8, 2) BSTAGE(16, 1)
    a[0] += __shfl_xor(a[0], 32);
    if (lane < 32) part[w][kmap] = a[0];
  }
  __syncthreads();
  if (t < 64) {
    int c = t & 31, q = t >> 5;
    float v;
    if (c < 16) v = part[0][q * 16 + c] + part[1][q * 16 + c];
    else        v = part[2][q * 16 + (c - 16)] + part[3][q * 16 + (c - 16)];
    bn_part[(size_t)b * 64 + q * 32 + c] = v;
  }
}

// ---------------------------------------------------------------- k2: BN coefficients
__global__ __launch_bounds__(256) void k2_stats(const float* __restrict__ bn_part,
                                                const float* __restrict__ gamma,
                                                const float* __restrict__ beta,
                                                float* __restrict__ coef) {
  __shared__ float sc[4][64];
  int t = threadIdx.x;
  int c = t & 63, q = t >> 6;
  float s = 0.f;
  for (int b = q; b < NB; b += 4) s += bn_part[b * 64 + c];
  sc[q][c] = s;
  __syncthreads();
  if (t < 64) sc[0][t] = sc[0][t] + sc[1][t] + sc[2][t] + sc[3][t];
  __syncthreads();
  if (t < 32) {
    const float inv = 1.f / (float)(NB * 128);
    float mean = sc[0][t] * inv;
    float var = sc[0][t + 32] * inv - mean * mean;
    float scl = gamma[t] * rsqrtf(var + 1e-5f);
    coef[t] = scl;
    coef[32 + t] = beta[t] - mean * scl;
  }
}

// ---------------------------------------------------------------- k3: BN apply + residual + leaky (in place)
__global__ __launch_bounds__(256) void k3_final(const float* __restrict__ xg,
                                                float* __restrict__ out,
                                                const float* __restrict__ coef) {
  __shared__ float s_c[64];
  if (threadIdx.x < 64) s_c[threadIdx.x] = coef[threadIdx.x];
  __syncthreads();
  size_t i4 = (size_t)blockIdx.x * 256 + threadIdx.x;
  float4 f = ((const float4*)out)[i4];
  float4 x = ((const float4*)xg)[i4];
  int c = (int)((i4 * 4) & 31);
  float4 r;
  r.x = x.x + f.x * s_c[c + 0] + s_c[32 + c + 0];
  r.y = x.y + f.y * s_c[c + 1] + s_c[32 + c + 1];
  r.z = x.z + f.z * s_c[c + 2] + s_c[32 + c + 2];
  r.w = x.w + f.w * s_c[c + 3] + s_c[32 + c + 3];
  r.x = r.x >= 0.f ? r.x : 0.2f * r.x;
  r.y = r.y >= 0.f ? r.y : 0.2f * r.y;
  r.z = r.z >= 0.f ? r.z : 0.2f * r.z;
  r.w = r.w >= 0.f ? r.w : 0.2f * r.w;
  ((float4*)out)[i4] = r;
}

// ----------------------------------------------------------------
extern "C" void kernel_launch(void* const* d_in, const int* in_sizes, int n_in,
                              void* d_out, int out_size, void* d_ws, size_t ws_size,
                              hipStream_t stream) {
  const float* xg    = (const float*)d_in[0];
  const float* xl    = (const float*)d_in[1];
  const float* W_lin = (const float*)d_in[2];
  const float* b_lin = (const float*)d_in[3];
  const float* W_att = (const float*)d_in[4];
  const float* Wa    = (const float*)d_in[5];
  const float* Wb    = (const float*)d_in[6];
  const float* Wc    = (const float*)d_in[7];
  const float* Wn    = (const float*)d_in[8];
  const float* Wl    = (const float*)d_in[9];
  const float* Wd    = (const float*)d_in[10];
  const float* gamma = (const float*)d_in[11];
  const float* beta  = (const float*)d_in[12];
  float* out = (float*)d_out;
  float* ws = (float*)d_ws;
  float* pre = ws;
  float* bn_part = ws + WS_BNPART;
  float* coef = ws + WS_COEF;
  float* p_small = ws + WS_SMALL;
  unsigned int* bigI = (unsigned int*)(ws + WS_BIG_I);
  unsigned int* bigV = (unsigned int*)(ws + WS_BIG_V);

  hipLaunchKernelGGL(k0_pre, dim3(1), dim3(256), 0, stream,
                     W_lin, b_lin, W_att, Wa, Wb, Wn, Wl, pre);
  hipLaunchKernelGGL(k1a, dim3(NB), dim3(256), 0, stream, xl, pre, p_small, bigI, bigV);
  hipLaunchKernelGGL(k1b, dim3(NB), dim3(256), 0, stream,
                     xg, Wc, Wd, p_small, bigI, bigV, out, bn_part);
  hipLaunchKernelGGL(k2_stats, dim3(1), dim3(256), 0, stream, bn_part, gamma, beta, coef);
  hipLaunchKernelGGL(k3_final, dim3(8192), dim3(256), 0, stream, xg, out, coef);
}